// Round 3
// baseline (75.018 us; speedup 1.0000x reference)
//
#include <hip/hip_runtime.h>
#include <math.h>

// Problem constants (from reference): DT=1, V_LAMBDA=1e-4, V_RIDGE=1e-4
#define LAM3  1e-4f   // V_LAMBDA / DT^6
#define RIDGE 1e-4f
#define NN    64      // N
#define NP    65      // N+1
#define ROWS  32      // batch rows per block: lanes 0..31 solve one row each

// (D3^T D3) band values for Np=65 (third-difference smoother), boundary-truncated.
__device__ __forceinline__ float d3_diag(int f) {
    if (f == 0 || f == 64) return 1.f;
    if (f == 1 || f == 63) return 10.f;
    if (f == 2 || f == 62) return 19.f;
    return 20.f;
}
__device__ __forceinline__ float d3_off1(int f) { // [f][f-1], valid f>=1
    if (f == 1 || f == 64) return -3.f;
    if (f == 2 || f == 63) return -12.f;
    return -15.f;
}
__device__ __forceinline__ float d3_off2(int f) { // [f][f-2], valid f>=2
    if (f == 2 || f == 64) return 3.f;
    return 6.f;
}

__global__ __launch_bounds__(64, 1) void alpamayo_banded_solve(
    const float* __restrict__ dxy,    // [B,64,2]
    const float* __restrict__ theta,  // [B,65]
    const float* __restrict__ v0,     // [B]
    float* __restrict__ out,          // [B,65]
    int B)
{
    // Lane-major layouts: element [idx][lane] -> bank = lane -> conflict-free.
    __shared__ float  th_s[NP * ROWS];        // [f][l]       8320 B
    __shared__ float  dx_s[128 * ROWS];       // [c][l]      16384 B
    __shared__ float2 L12s[NN * ROWS];        // [i][l] (Li1,Li2) 16384 B
    __shared__ float  rds [NN * ROWS];        // [i][l] rd    8192 B
    __shared__ float  outs[NP * ROWS];        // [l][j] row-major == out layout, 8320 B
    __shared__ float4 Atab[NN];               // (a0, a1c, a2, v0-coeff) 1024 B

    const int lane = threadIdx.x;
    long base = (long)blockIdx.x * ROWS;
    bool fastB = true;
    if (base + ROWS > B) {
        base = B - ROWS;                      // duplicate tail rows; identical writes -> benign
        if (base < 0) { base = 0; fastB = false; }  // B < ROWS: rare guarded path
    }

    // ---- Coefficient table (one-time, divergent but tiny) ----
    if (lane < NN) {
        const int f = lane + 1;
        const float a0  = (f == NN ? 1.f : 2.f) + LAM3 * d3_diag(f) + RIDGE;
        const float a1c = LAM3 * d3_off1(f);
        const float a2  = LAM3 * d3_off2(f);
        float cv = 0.f;                       // rhs v0-correction coefficient
        if (lane == 0) cv = -3.f * LAM3;      // (e-term added in-loop)
        if (lane == 1) cv =  3.f * LAM3;
        if (lane == 2) cv = -1.f * LAM3;
        Atab[lane] = make_float4(a0, a1c, a2, cv);
    }

    // ---- Staging: global -> LDS, transpose-mapped, UNGUARDED (fast path) ----
    if (fastB) {
        const int lo = lane & 31, hi = lane >> 5;
        // theta: LDS word q = w*64+lane == f*32+l with f=2w+hi, l=lo; src = row lo, elem f
        const float* tg = theta + (base + lo) * NP + hi;
        #pragma unroll
        for (int w = 0; w < 32; ++w) th_s[w * 64 + lane] = tg[2 * w];
        if (lane < 32) th_s[NN * 32 + lane] = theta[(base + lane) * NP + NN];  // f=64 tail
        // dxy: q = w*64+lane == c*32+l with c=2w+hi
        const float* dg_ = dxy + (base + lo) * (2 * NN) + hi;
        #pragma unroll
        for (int w = 0; w < 64; ++w) dx_s[w * 64 + lane] = dg_[2 * w];
    } else {
        // B < ROWS: per-lane guarded row copies (slow but correct, rarely taken)
        if (lane < B) {
            for (int f = 0; f < NP; ++f)  th_s[f * 32 + lane] = theta[((long)lane) * NP + f];
            for (int c = 0; c < 128; ++c) dx_s[c * 32 + lane] = dxy[((long)lane) * (2 * NN) + c];
        }
    }
    long v0i = base + (lane & 31); if (v0i > (long)B - 1) v0i = B - 1;
    const float v0b = v0[v0i];

    __syncthreads();

    // ---- Solve: lanes 0..31, one row each. Rolled loops + 1-ahead LDS prefetch ----
    if (lane < ROWS) {
        const int l = lane;
        float cp, sp;
        __sincosf(th_s[0 * 32 + l], &sp, &cp);
        float xc = dx_s[0 * 32 + l], yc = dx_s[1 * 32 + l];
        float thn = th_s[1 * 32 + l];
        float xn  = dx_s[2 * 32 + l], yn = dx_s[3 * 32 + l];

        float p1L1 = 0.f, p1L2 = 0.f, p2L1 = 0.f;
        float rd1 = 0.f, rd2 = 0.f, rd3 = 0.f;
        float z1 = 0.f, z2 = 0.f, z3 = 0.f;
        float* oz = outs + l * NP;
        oz[0] = v0b;

        #pragma unroll 4
        for (int i = 0; i < NN; ++i) {
            const int f = i + 1;
            const float thf = thn;
            const float xf = xn, yf = yn;
            // prefetch next iteration's inputs (clamped; masked at consume)
            const int f2 = (f < NN) ? f + 1 : NN;
            thn = th_s[f2 * 32 + l];
            const int c2 = (f < NN - 1) ? 2 * f + 2 : 126;
            xn = dx_s[c2 * 32 + l];
            yn = dx_s[(c2 + 1) * 32 + l];

            float cf, sf;
            __sincosf(thf, &sf, &cf);
            const float e  = cf * cp + sf * sp;          // cos(theta_f - theta_{f-1})
            const float xs = (f < NN) ? xf : 0.f;
            const float ys = (f < NN) ? yf : 0.f;
            const float4 a = Atab[i];
            float rr = 2.f * (cf * (xc + xs) + sf * (yc + ys));
            rr -= a.w * v0b;
            if (i == 0) rr -= e * v0b;                   // uniform branch

            const float a1  = e + a.y;
            const float Li3 = (-LAM3) * rd3;             // killed by rd3=0 for i<3
            const float Li2 = (a.z - Li3 * p2L1) * rd2;  // killed by rd2=0 for i<2
            const float Li1 = (a1 - Li3 * p1L2 - Li2 * p1L1) * rd1;
            const float dg  = a.x - Li3 * Li3 - Li2 * Li2 - Li1 * Li1;
            const float rd0 = __builtin_amdgcn_rsqf(dg);
            const float zi  = (rr - Li3 * z3 - Li2 * z2 - Li1 * z1) * rd0;

            L12s[i * 32 + l] = make_float2(Li1, Li2);
            rds [i * 32 + l] = rd0;
            oz[1 + i] = zi;                              // z staged in output slot

            p2L1 = p1L1; p1L1 = Li1; p1L2 = Li2;
            rd3 = rd2; rd2 = rd1; rd1 = rd0;
            z3 = z2; z2 = z1; z1 = zi;
            cp = cf; sp = sf; xc = xs; yc = ys;
        }

        // ---- Back substitution (rolled, 1-ahead prefetch); y overwrites z in outs ----
        float r1L1 = 0.f, r1L2 = 0.f, r1L3 = 0.f;
        float r2L2 = 0.f, r2L3 = 0.f, r3L3 = 0.f;
        float y1 = 0.f, y2 = 0.f, y3 = 0.f;

        float2 Lc  = L12s[(NN - 1) * 32 + l];
        float  rdc = rds [(NN - 1) * 32 + l];
        float  zc  = oz[NN];
        float  rm3 = rds [(NN - 4) * 32 + l];

        #pragma unroll 4
        for (int i = NN - 1; i >= 0; --i) {
            const float L1i = Lc.x, L2i = Lc.y, rdi = rdc, zi = zc, rdm3 = rm3;
            const int ip  = (i > 0)  ? i - 1 : 0;        // prefetch next (i-1)
            Lc  = L12s[ip * 32 + l];
            rdc = rds [ip * 32 + l];
            zc  = oz[ip + 1];
            const int im4 = (i >= 4) ? i - 4 : 0;
            rm3 = rds[im4 * 32 + l];

            const float L3i = (i >= 3) ? (-LAM3) * rdm3 : 0.f;   // Li3 = -lam*rd[i-3]
            const float yi  = (zi - r1L1 * y1 - r2L2 * y2 - r3L3 * y3) * rdi;
            oz[1 + i] = yi;

            r3L3 = r2L3; r2L3 = r1L3; r2L2 = r1L2;
            r1L1 = L1i;  r1L2 = L2i;  r1L3 = L3i;
            y3 = y2; y2 = y1; y1 = yi;
        }
    }

    __syncthreads();

    // ---- Coalesced LDS -> global output sweep (outs is exactly out-layout) ----
    {
        long nv = B - base; if (nv > ROWS) nv = ROWS;
        const int nvalid = (int)nv * NP;                 // 2080 in the common case
        float* og = out + base * NP;
        #pragma unroll
        for (int w = 0; w < 33; ++w) {
            const int q = w * 64 + lane;
            if (q < nvalid) og[q] = outs[q];             // predicated stores only
        }
    }
}

extern "C" void kernel_launch(void* const* d_in, const int* in_sizes, int n_in,
                              void* d_out, int out_size, void* d_ws, size_t ws_size,
                              hipStream_t stream) {
    const float* dxy   = (const float*)d_in[0];   // [B,64,2]
    const float* theta = (const float*)d_in[1];   // [B,65]
    const float* v0    = (const float*)d_in[2];   // [B]
    float* out = (float*)d_out;                   // [B,65]
    const int B = in_sizes[2];
    const int blocks = (B + ROWS - 1) / ROWS;     // 256 blocks -> one wave per CU
    alpamayo_banded_solve<<<blocks, 64, 0, stream>>>(dxy, theta, v0, out, B);
}

// Round 4
// 73.148 us; speedup vs baseline: 1.0256x; 1.0256x over previous
//
#include <hip/hip_runtime.h>
#include <math.h>

// Problem constants (from reference): DT=1, V_LAMBDA=1e-4, V_RIDGE=1e-4
#define LAM3  1e-4f   // V_LAMBDA / DT^6
#define RIDGE 1e-4f
#define NN    64      // N
#define NP    65      // N+1
#define ROWS  32      // batch rows per block: lanes 0..31 solve one row each

// (D3^T D3) band values for Np=65 (third-difference smoother), boundary-truncated.
__device__ __forceinline__ float d3_diag(int f) {
    if (f == 0 || f == 64) return 1.f;
    if (f == 1 || f == 63) return 10.f;
    if (f == 2 || f == 62) return 19.f;
    return 20.f;
}
__device__ __forceinline__ float d3_off1(int f) { // [f][f-1], valid f>=1
    if (f == 1 || f == 64) return -3.f;
    if (f == 2 || f == 63) return -12.f;
    return -15.f;
}
__device__ __forceinline__ float d3_off2(int f) { // [f][f-2], valid f>=2
    if (f == 2 || f == 64) return 3.f;
    return 6.f;
}

__global__ __launch_bounds__(64, 1) void alpamayo_banded_solve(
    const float* __restrict__ dxy,    // [B,64,2]
    const float* __restrict__ theta,  // [B,65]
    const float* __restrict__ v0,     // [B]
    float* __restrict__ out,          // [B,65]
    int B)
{
    // All arrays DISTINCT and single-direction per loop (no intra-loop RW on any
    // one array -> alias analysis succeeds -> unroll-4 hoists prefetch reads).
    __shared__ float  th_s[ROWS * NP];        // [l][f] stride 65 (odd)   8320 B  read-only after stage
    __shared__ float  dx_s[ROWS * 130];       // [l][c] stride 130        16640 B read-only after stage
    __shared__ float2 Ls2 [NN * ROWS];        // [i][l] (Li1,Li2)         16384 B fwd:W  back:R
    __shared__ float  rds [NN * ROWS];        // [i][l] rd                 8192 B fwd:W  back:R
    __shared__ float  zs  [NN * ROWS];        // [i][l] z                  8192 B fwd:W  back:R
    __shared__ float4 Atab[NN];               // (a0, a1c, a2, v0coeff)    1024 B
    // total 58752 B

    const int lane = threadIdx.x;
    long base = (long)blockIdx.x * ROWS;
    bool fastB = true;
    if (base + ROWS > B) {
        base = B - ROWS;                      // duplicate tail rows; identical stores -> benign
        if (base < 0) { base = 0; fastB = false; }  // B < ROWS: rare guarded path
    }
    const int rowsValid = (B - base < ROWS) ? (int)(B - base) : ROWS;

    // ---- Coefficient table (all 64 lanes, one entry each) ----
    {
        const int f = lane + 1;
        const float a0  = (f == NN ? 1.f : 2.f) + LAM3 * d3_diag(f) + RIDGE;
        const float a1c = LAM3 * d3_off1(f);
        const float a2  = LAM3 * d3_off2(f);
        float cv = 0.f;
        if (lane == 0) cv = -3.f * LAM3;
        if (lane == 1) cv =  3.f * LAM3;
        if (lane == 2) cv = -1.f * LAM3;
        Atab[lane] = make_float4(a0, a1c, a2, cv);
    }

    // ---- Staging: flat coalesced global -> LDS, UNGUARDED on the fast path ----
    if (fastB) {
        const float* thg = theta + base * NP;         // 2080 contiguous words
        #pragma unroll
        for (int w = 0; w < 32; ++w) th_s[w * 64 + lane] = thg[w * 64 + lane];
        if (lane < 32) th_s[2048 + lane] = thg[2048 + lane];

        const float* dg = dxy + base * (2 * NN);      // 4096 contiguous words
        #pragma unroll
        for (int w = 0; w < 64; ++w) {
            const int q = w * 64 + lane;
            dx_s[q + 2 * (q >> 7)] = dg[q];           // row-major stride 130; (q>>7) sweep-uniform
        }
    } else {
        if (lane < B) {
            for (int f = 0; f < NP; ++f)  th_s[lane * NP + f]  = theta[(long)lane * NP + f];
            for (int c = 0; c < 2 * NN; ++c) dx_s[lane * 130 + c] = dxy[(long)lane * (2 * NN) + c];
        }
    }
    long v0i = base + (lane & 31); if (v0i > (long)B - 1) v0i = B - 1;
    const float v0b = v0[v0i];

    __syncthreads();

    if (lane < ROWS) {
        const int  l    = lane;
        const bool live = (l < rowsValid);
        const float* thp = th_s + l * NP;
        const float* dxp = dx_s + l * 130;
        float* og = out + (base + l) * NP;

        // ---- Forward: fused Cholesky + substitution. LDS: read th/dx/Atab, write Ls/rds/zs ----
        float cp, sp;
        __sincosf(thp[0], &sp, &cp);
        float xc = dxp[0], yc = dxp[1];
        float thn = thp[1];
        float xn = dxp[2], yn = dxp[3];
        float4 an = Atab[0];

        float p1L1 = 0.f, p1L2 = 0.f, p2L1 = 0.f;
        float rd1 = 0.f, rd2 = 0.f, rd3 = 0.f;
        float z1 = 0.f, z2 = 0.f, z3 = 0.f;

        #pragma unroll 4
        for (int i = 0; i < NN; ++i) {
            const int f = i + 1;
            const float thf = thn;
            const float xf = xn, yf = yn;
            const float4 a = an;
            // prefetch next iteration (clamped; garbage masked at consume)
            const int f2 = (f < NN) ? f + 1 : NN;
            thn = thp[f2];
            const int c2 = (f < NN - 1) ? 2 * f + 2 : 126;
            xn = dxp[c2]; yn = dxp[c2 + 1];
            an = Atab[(i < NN - 1) ? i + 1 : NN - 1];

            float cf, sf;
            __sincosf(thf, &sf, &cf);
            const float e  = cf * cp + sf * sp;          // cos(theta_f - theta_{f-1})
            const float xs = (f < NN) ? xf : 0.f;
            const float ys = (f < NN) ? yf : 0.f;
            float rr = 2.f * (cf * (xc + xs) + sf * (yc + ys));
            rr -= a.w * v0b;
            if (i == 0) rr -= e * v0b;                   // uniform

            const float a1  = e + a.y;
            const float Li3 = (-LAM3) * rd3;             // killed by rd3=0 for i<3
            const float Li2 = (a.z - Li3 * p2L1) * rd2;  // killed by rd2=0 for i<2
            const float Li1 = (a1 - Li3 * p1L2 - Li2 * p1L1) * rd1;
            const float dg  = a.x - Li3 * Li3 - Li2 * Li2 - Li1 * Li1;
            const float rd0 = __builtin_amdgcn_rsqf(dg);
            const float zi  = (rr - Li3 * z3 - Li2 * z2 - Li1 * z1) * rd0;

            Ls2[i * ROWS + l] = make_float2(Li1, Li2);   // write-only this loop
            rds[i * ROWS + l] = rd0;
            zs [i * ROWS + l] = zi;

            p2L1 = p1L1; p1L1 = Li1; p1L2 = Li2;
            rd3 = rd2; rd2 = rd1; rd1 = rd0;
            z3 = z2; z2 = z1; z1 = zi;
            cp = cf; sp = sf; xc = xs; yc = ys;
        }

        // ---- Backward: LDS read-only (Ls/rds/zs), stores go straight to global ----
        if (live) og[0] = v0b;

        float r1L1 = 0.f, r1L2 = 0.f, r1L3 = 0.f;
        float r2L2 = 0.f, r2L3 = 0.f, r3L3 = 0.f;
        float y1 = 0.f, y2 = 0.f, y3 = 0.f;

        float2 Lc  = Ls2[(NN - 1) * ROWS + l];
        float  rdc = rds[(NN - 1) * ROWS + l];
        float  zc  = zs [(NN - 1) * ROWS + l];
        float  rm3 = rds[(NN - 4) * ROWS + l];

        #pragma unroll 4
        for (int i = NN - 1; i >= 0; --i) {
            const float L1i = Lc.x, L2i = Lc.y, rdi = rdc, zi = zc, rdm3 = rm3;
            const int ip = (i > 0) ? i - 1 : 0;          // prefetch next (i-1)
            Lc  = Ls2[ip * ROWS + l];
            rdc = rds[ip * ROWS + l];
            zc  = zs [ip * ROWS + l];
            const int im4 = (i >= 4) ? i - 4 : 0;
            rm3 = rds[im4 * ROWS + l];

            const float L3i = (i >= 3) ? (-LAM3) * rdm3 : 0.f;   // Li3 = -lam*rd[i-3]
            const float yi  = (zi - r1L1 * y1 - r2L2 * y2 - r3L3 * y3) * rdi;
            if (live) og[1 + i] = yi;                    // off-chain scalar store

            r3L3 = r2L3; r2L3 = r1L3; r2L2 = r1L2;
            r1L1 = L1i;  r1L2 = L2i;  r1L3 = L3i;
            y3 = y2; y2 = y1; y1 = yi;
        }
    }
}

extern "C" void kernel_launch(void* const* d_in, const int* in_sizes, int n_in,
                              void* d_out, int out_size, void* d_ws, size_t ws_size,
                              hipStream_t stream) {
    const float* dxy   = (const float*)d_in[0];   // [B,64,2]
    const float* theta = (const float*)d_in[1];   // [B,65]
    const float* v0    = (const float*)d_in[2];   // [B]
    float* out = (float*)d_out;                   // [B,65]
    const int B = in_sizes[2];
    const int blocks = (B + ROWS - 1) / ROWS;     // 256 blocks -> one wave per CU
    alpamayo_banded_solve<<<blocks, 64, 0, stream>>>(dxy, theta, v0, out, B);
}

// Round 6
// 64.325 us; speedup vs baseline: 1.1662x; 1.1372x over previous
//
#include <hip/hip_runtime.h>
#include <math.h>

// Problem constants (from reference): DT=1, V_LAMBDA=1e-4, V_RIDGE=1e-4
#define LAM3  1e-4f   // V_LAMBDA / DT^6
#define RIDGE 1e-4f
#define NN    64      // N
#define NP    65      // N+1

// (D3^T D3) band values for Np=65 (third-difference smoother), boundary-truncated.
// Fully constant-folded per iteration under #pragma unroll.
__device__ __forceinline__ float d3_diag(int f) {
    if (f == 0 || f == 64) return 1.f;
    if (f == 1 || f == 63) return 10.f;
    if (f == 2 || f == 62) return 19.f;
    return 20.f;
}
__device__ __forceinline__ float d3_off1(int f) { // [f][f-1], valid f>=1
    if (f == 1 || f == 64) return -3.f;
    if (f == 2 || f == 63) return -12.f;
    return -15.f;
}
__device__ __forceinline__ float d3_off2(int f) { // [f][f-2], valid f>=2
    if (f == 2 || f == 64) return 3.f;
    return 6.f;
}
// [f][f-3] == -1 everywhere it exists (f>=3)

__global__ __launch_bounds__(64, 1) void alpamayo_banded_solve(
    const float* __restrict__ dxy,    // [B,64,2]
    const float* __restrict__ theta,  // [B,65]
    const float* __restrict__ v0,     // [B]
    float* __restrict__ out,          // [B,65]
    int B)
{
    // Per-thread column layout: no cross-thread sharing -> no barriers needed.
    __shared__ float4 Lrec[NN][64];   // 64 KiB

    const int tid = threadIdx.x;
    const int b = blockIdx.x * 64 + tid;
    if (b >= B) return;

    const float* th = theta + (long)b * NP;
    const float4* dx4 = (const float4*)(dxy + (long)b * (2 * NN)); // 512B row stride -> aligned
    const float v0b = v0[b];

    // ---- Preload ALL inputs into registers (batched, one vmcnt drain) ----
    float dxf[2 * NN];
    #pragma unroll
    for (int j = 0; j < 32; ++j) {
        const float4 q = dx4[j];
        dxf[4 * j + 0] = q.x; dxf[4 * j + 1] = q.y;
        dxf[4 * j + 2] = q.z; dxf[4 * j + 3] = q.w;
    }
    float thr[NP];
    #pragma unroll
    for (int f = 0; f < NP; ++f) thr[f] = th[f];

    float* outp = out + (long)b * NP;
    outp[0] = v0b;                       // fire early, off-chain

    // ---- FUSED: sincos + e + rhs + banded Cholesky + forward substitution ----
    // Single unrolled loop; no e[]/rhs[] register arrays (saves ~128 VGPRs and
    // ~20-25% of the unrolled instruction stream vs the two-loop version).
    float z[NN];
    float cp, sp;
    __sincosf(thr[0], &sp, &cp);
    float xc = dxf[0], yc = dxf[1];

    float p1L1 = 0.f, p1L2 = 0.f, p2L1 = 0.f;
    float rd1 = 0.f, rd2 = 0.f, rd3 = 0.f;
    float z1 = 0.f, z2 = 0.f, z3 = 0.f;

    #pragma unroll
    for (int i = 0; i < NN; ++i) {
        const int f = i + 1;
        float cf, sf;
        __sincosf(thr[f], &sf, &cf);
        const float e  = cf * cp + sf * sp;            // cos(theta_f - theta_{f-1})
        const float xs = (f < NN) ? dxf[2 * f]     : 0.f;
        const float ys = (f < NN) ? dxf[2 * f + 1] : 0.f;
        float rr = 2.f * (cf * (xc + xs) + sf * (yc + ys));
        // v0 corrections (couplings of reduced rows 0..2 to full index 0);
        // compile-time selected by the unroll.
        if (i == 0) rr -= (e + LAM3 * -3.f) * v0b;
        if (i == 1) rr -= (LAM3 *  3.f) * v0b;
        if (i == 2) rr -= (LAM3 * -1.f) * v0b;

        const float a0 = (f == NN ? 1.f : 2.f) + LAM3 * d3_diag(f) + RIDGE;  // const
        const float a1 = e + LAM3 * d3_off1(f);
        const float a2 = LAM3 * d3_off2(f);                                  // const

        const float Li3 = (-LAM3) * rd3;               // killed by rd3=0 for i<3
        const float Li2 = (a2 - Li3 * p2L1) * rd2;     // killed by rd2=0 for i<2
        const float Li1 = (a1 - Li3 * p1L2 - Li2 * p1L1) * rd1;
        const float dg  = a0 - Li3 * Li3 - Li2 * Li2 - Li1 * Li1;
        const float rd0 = __builtin_amdgcn_rsqf(dg);
        const float zi  = (rr - Li3 * z3 - Li2 * z2 - Li1 * z1) * rd0;

        Lrec[i][tid] = make_float4(Li1, Li2, Li3, rd0);
        z[i] = zi;

        p2L1 = p1L1; p1L1 = Li1; p1L2 = Li2;
        rd3 = rd2; rd2 = rd1; rd1 = rd0;
        z3 = z2; z2 = z1; z1 = zi;
        cp = cf; sp = sf; xc = xs; yc = ys;
    }

    // ---- Back substitution (identical to the proven r0 version) ----
    float r1L1 = 0.f, r1L2 = 0.f, r1L3 = 0.f;
    float r2L2 = 0.f, r2L3 = 0.f;
    float r3L3 = 0.f;
    float y1 = 0.f, y2 = 0.f, y3 = 0.f;

    #pragma unroll
    for (int i = NN - 1; i >= 0; --i) {
        const float4 rec = Lrec[i][tid];
        const float yi = (z[i] - r1L1 * y1 - r2L2 * y2 - r3L3 * y3) * rec.w;
        outp[1 + i] = yi;
        r3L3 = r2L3; r2L3 = r1L3; r2L2 = r1L2;
        r1L1 = rec.x; r1L2 = rec.y; r1L3 = rec.z;
        y3 = y2; y2 = y1; y1 = yi;
    }
}

extern "C" void kernel_launch(void* const* d_in, const int* in_sizes, int n_in,
                              void* d_out, int out_size, void* d_ws, size_t ws_size,
                              hipStream_t stream) {
    const float* dxy   = (const float*)d_in[0];   // [B,64,2]
    const float* theta = (const float*)d_in[1];   // [B,65]
    const float* v0    = (const float*)d_in[2];   // [B]
    float* out = (float*)d_out;                   // [B,65]
    const int B = in_sizes[2];
    const int blocks = (B + 63) / 64;
    alpamayo_banded_solve<<<blocks, 64, 0, stream>>>(dxy, theta, v0, out, B);
}